// Round 9
// baseline (209.467 us; speedup 1.0000x reference)
//
#include <hip/hip_runtime.h>

// Problem constants (static shapes from reference)
#define B 64
#define C 2048
#define H 24
#define W 8
#define HW (H * W)            // 192 spatial positions per (b,c)
#define HW4 (HW / 4)          // 48 float4 per channel row
#define CHUNKS 16             // channel chunks per batch
#define CPC (C / CHUNKS)      // 128 channels per chunk
#define RH 8                  // round(0.33 * 24) = 8 rows dropped
#define CHW4 ((C * HW) / 4)   // float4s per batch = 98304
#define TPB 192               // 3 waves (k1)
#define ZBLKS 32              // zero-blocks per batch (k2)
#define ZTPB 256              // k2 block size

typedef float f32x4 __attribute__((ext_vector_type(4)));

// ---------------------------------------------------------------------------
// Kernel 1: sumsq partials + copy out = x, single pass over x.
// R8 ran this at 2.4 TB/s: NT stores ack from near-HBM (~600-900 cyc) and the
// register-reuse vmcnt wait serialized the pipeline at ~2 buffers/thread.
// Fixes: (a) REGULAR stores -> ack at L2 (~200 cyc); L3 holds x+out = 200 MB
// < 256 MB so x stays resident. (b) 4-deep explicit load batches -> 4 loads
// in flight before the first dependent store. FP accumulation order
// (j = 0..31 sequential) is preserved EXACTLY -> mask bit-identical.
// ---------------------------------------------------------------------------
__global__ __launch_bounds__(TPB) void k_ss_copy(const f32x4* __restrict__ x4,
                                                 f32x4* __restrict__ partial4,
                                                 f32x4* __restrict__ out4) {
    const int blk = blockIdx.x;
    const int b = blk / CHUNKS;
    const int chunk = blk % CHUNKS;
    const int t = threadIdx.x;
    const int q = t % HW4;   // float4 spatial position
    const int g = t / HW4;   // channel subgroup (0..3)

    const size_t xoff = (size_t)(b * C + chunk * CPC + g) * HW4 + q;
    const f32x4* p = x4 + xoff;
    f32x4* o = out4 + xoff;

    f32x4 acc = {0.f, 0.f, 0.f, 0.f};
    #pragma unroll
    for (int jj = 0; jj < CPC / 16; ++jj) {      // 8 groups of 4 iterations
        const size_t s0 = (size_t)(jj * 4 + 0) * 4 * HW4;
        const size_t s1 = (size_t)(jj * 4 + 1) * 4 * HW4;
        const size_t s2 = (size_t)(jj * 4 + 2) * 4 * HW4;
        const size_t s3 = (size_t)(jj * 4 + 3) * 4 * HW4;
        const f32x4 v0 = p[s0];                  // 4 independent loads in flight
        const f32x4 v1 = p[s1];
        const f32x4 v2 = p[s2];
        const f32x4 v3 = p[s3];
        acc += v0 * v0;                          // same j-sequence as verified
        acc += v1 * v1;
        acc += v2 * v2;
        acc += v3 * v3;
        o[s0] = v0;                              // regular stores: L2-ack'd
        o[s1] = v1;
        o[s2] = v2;
        o[s3] = v3;
    }
    __shared__ f32x4 sm[4][HW4];  // 3 KB
    sm[g][q] = acc;
    __syncthreads();
    if (t < HW4)
        partial4[(size_t)blk * HW4 + t] =          // L2-hot for k2
            (sm[0][t] + sm[1][t]) + (sm[2][t] + sm[3][t]);
}

// ---------------------------------------------------------------------------
// Kernel 2 (verbatim R8, passed absmax 0): rank rows redundantly per block,
// ballot-compact the RH dropped rows, zero-fill this block's slice.
// Writes only 33.5 MB. NT stores are fine here: the zero register is never
// reloaded, so there is no vmcnt reuse chain; NT avoids polluting L3 (which
// should keep holding x for the next iteration's k1).
// ---------------------------------------------------------------------------
__global__ __launch_bounds__(ZTPB) void k_mask_zero(const f32x4* __restrict__ partial4,
                                                    f32x4* __restrict__ out4) {
    const int b = blockIdx.x / ZBLKS;
    const int s = blockIdx.x % ZBLKS;
    const int t = threadIdx.x;
    __shared__ int drp[RH];

    // ---- Rank rows (wave 0; verbatim verified shuffle math) ----
    if (t < 64) {
        f32x4 sum = {0.f, 0.f, 0.f, 0.f};
        if (t < HW4) {
            #pragma unroll
            for (int ch = 0; ch < CHUNKS; ++ch)  // fixed order: deterministic
                sum += partial4[(size_t)(b * CHUNKS + ch) * HW4 + t];
        }
        float m = fmaxf(fmaxf(sum.x, sum.y), fmaxf(sum.z, sum.w));
        m = fmaxf(m, __shfl_xor(m, 1));  // row h max now at lane 2h
        const float my = __shfl(m, 2 * (t < H ? t : 0));
        int cnt = 0;
        #pragma unroll
        for (int h = 0; h < H; ++h) {
            const float o = __shfl(m, 2 * h);
            if (o > my || (o == my && h > t)) ++cnt;  // stable-argsort tie-break
        }
        const bool pred = (t < H) && (cnt < RH);
        const unsigned long long ball = __ballot(pred);
        if (pred) {
            const int rank = __popcll(ball & ((1ull << t) - 1ull));
            drp[rank] = t;  // exactly RH entries
        }
    }
    __syncthreads();

    // ---- Zero this block's slice of the dropped rows ----
    const size_t ob = (size_t)b * CHW4;
    const f32x4 z = {0.f, 0.f, 0.f, 0.f};
    #pragma unroll
    for (int r = 0; r < 4; ++r) {
        const int j = s * (ZTPB * 4) + r * ZTPB + t;
        const int c = j >> 4;
        const int k = (j & 15) >> 1;
        const int w4 = j & 1;
        const size_t e = ob + (size_t)c * HW4 + (size_t)drp[k] * 2 + w4;
        __builtin_nontemporal_store(z, (f32x4*)(out4 + e));
    }
}

// ---------------------------------------------------------------------------
extern "C" void kernel_launch(void* const* d_in, const int* in_sizes, int n_in,
                              void* d_out, int out_size, void* d_ws, size_t ws_size,
                              hipStream_t stream) {
    const f32x4* x4 = (const f32x4*)d_in[0];
    f32x4* out4 = (f32x4*)d_out;
    f32x4* partial4 = (f32x4*)d_ws;  // B*CHUNKS*HW floats (768 KB)

    k_ss_copy<<<B * CHUNKS, TPB, 0, stream>>>(x4, partial4, out4);
    k_mask_zero<<<B * ZBLKS, ZTPB, 0, stream>>>(partial4, out4);
}

// Round 10
// 206.553 us; speedup vs baseline: 1.0141x; 1.0141x over previous
//
#include <hip/hip_runtime.h>

// Problem constants (static shapes from reference)
#define B 64
#define C 2048
#define H 24
#define W 8
#define HW (H * W)            // 192 spatial positions per (b,c)
#define HW4 (HW / 4)          // 48 float4 per channel row
#define CHUNKS 16             // channel chunks per batch
#define CPC (C / CHUNKS)      // 128 channels per chunk
#define RH 8                  // round(0.33 * 24) = 8 rows dropped
#define CHW4 ((C * HW) / 4)   // float4s per batch = 98304
#define TPB 192               // 3 waves (k1)
#define ZBLKS 32              // zero-blocks per batch (k2)
#define ZTPB 256              // k2 block size

typedef float f32x4 __attribute__((ext_vector_type(4)));

// ---------------------------------------------------------------------------
// Kernel 1: sumsq partials + copy out = x, single pass over x.
// Lessons baked in:
//   R8: NT stores + 2 payload regs -> every load waited on a prior NT store
//       ack from near-HBM -> 2.4 TB/s. Fills stayed fast (59 us).
//   R9: regular stores -> k1 faster BUT ~100 MB of dirty out lines made the
//       harness poison fills pay writeback: fills 59 -> 73 us. Net loss.
// Fix: NT stores (keep fills fast) + EXPLICIT 32-deep register staging so
// loads never reuse a register a pending store holds: load all 32 float4
// into named arrays (static indices -> registers), accumulate in the exact
// verified j=0..31 order (mask bit-identical), then drain all 32 NT stores.
// VGPR ~160 fits 3 waves/SIMD (12 waves/CU at this 1024-block grid).
// ---------------------------------------------------------------------------
__global__ __launch_bounds__(TPB) void k_ss_copy(const f32x4* __restrict__ x4,
                                                 f32x4* __restrict__ partial4,
                                                 f32x4* __restrict__ out4) {
    const int blk = blockIdx.x;
    const int b = blk / CHUNKS;
    const int chunk = blk % CHUNKS;
    const int t = threadIdx.x;
    const int q = t % HW4;   // float4 spatial position
    const int g = t / HW4;   // channel subgroup (0..3)

    const size_t xoff = (size_t)(b * C + chunk * CPC + g) * HW4 + q;
    const f32x4* p = x4 + xoff;
    f32x4* o = out4 + xoff;

    f32x4 v[16], u[16];
    #pragma unroll
    for (int j = 0; j < 16; ++j) v[j] = p[(size_t)j * 4 * HW4];         // 16 in flight
    #pragma unroll
    for (int j = 0; j < 16; ++j) u[j] = p[(size_t)(j + 16) * 4 * HW4];  // 32 in flight

    f32x4 acc = {0.f, 0.f, 0.f, 0.f};
    #pragma unroll
    for (int j = 0; j < 16; ++j) acc += v[j] * v[j];  // exact verified j-order
    #pragma unroll
    for (int j = 0; j < 16; ++j) acc += u[j] * u[j];

    #pragma unroll
    for (int j = 0; j < 16; ++j)
        __builtin_nontemporal_store(v[j], o + (size_t)j * 4 * HW4);
    #pragma unroll
    for (int j = 0; j < 16; ++j)
        __builtin_nontemporal_store(u[j], o + (size_t)(j + 16) * 4 * HW4);

    __shared__ f32x4 sm[4][HW4];  // 3 KB
    sm[g][q] = acc;
    __syncthreads();
    if (t < HW4)
        partial4[(size_t)blk * HW4 + t] =          // regular store: tiny, L2-hot for k2
            (sm[0][t] + sm[1][t]) + (sm[2][t] + sm[3][t]);
}

// ---------------------------------------------------------------------------
// Kernel 2 (verbatim R8, passed absmax 0): rank rows redundantly per block,
// ballot-compact the RH dropped rows, zero-fill this block's slice.
// Writes only 33.5 MB, nontemporal (zero reg never reloaded -> no ack chain;
// keeps L3 clean for the next iteration's fills).
// ---------------------------------------------------------------------------
__global__ __launch_bounds__(ZTPB) void k_mask_zero(const f32x4* __restrict__ partial4,
                                                    f32x4* __restrict__ out4) {
    const int b = blockIdx.x / ZBLKS;
    const int s = blockIdx.x % ZBLKS;
    const int t = threadIdx.x;
    __shared__ int drp[RH];

    // ---- Rank rows (wave 0; verbatim verified shuffle math) ----
    if (t < 64) {
        f32x4 sum = {0.f, 0.f, 0.f, 0.f};
        if (t < HW4) {
            #pragma unroll
            for (int ch = 0; ch < CHUNKS; ++ch)  // fixed order: deterministic
                sum += partial4[(size_t)(b * CHUNKS + ch) * HW4 + t];
        }
        float m = fmaxf(fmaxf(sum.x, sum.y), fmaxf(sum.z, sum.w));
        m = fmaxf(m, __shfl_xor(m, 1));  // row h max now at lane 2h
        const float my = __shfl(m, 2 * (t < H ? t : 0));
        int cnt = 0;
        #pragma unroll
        for (int h = 0; h < H; ++h) {
            const float o = __shfl(m, 2 * h);
            if (o > my || (o == my && h > t)) ++cnt;  // stable-argsort tie-break
        }
        const bool pred = (t < H) && (cnt < RH);
        const unsigned long long ball = __ballot(pred);
        if (pred) {
            const int rank = __popcll(ball & ((1ull << t) - 1ull));
            drp[rank] = t;  // exactly RH entries
        }
    }
    __syncthreads();

    // ---- Zero this block's slice of the dropped rows ----
    const size_t ob = (size_t)b * CHW4;
    const f32x4 z = {0.f, 0.f, 0.f, 0.f};
    #pragma unroll
    for (int r = 0; r < 4; ++r) {
        const int j = s * (ZTPB * 4) + r * ZTPB + t;
        const int c = j >> 4;
        const int k = (j & 15) >> 1;
        const int w4 = j & 1;
        const size_t e = ob + (size_t)c * HW4 + (size_t)drp[k] * 2 + w4;
        __builtin_nontemporal_store(z, (f32x4*)(out4 + e));
    }
}

// ---------------------------------------------------------------------------
extern "C" void kernel_launch(void* const* d_in, const int* in_sizes, int n_in,
                              void* d_out, int out_size, void* d_ws, size_t ws_size,
                              hipStream_t stream) {
    const f32x4* x4 = (const f32x4*)d_in[0];
    f32x4* out4 = (f32x4*)d_out;
    f32x4* partial4 = (f32x4*)d_ws;  // B*CHUNKS*HW floats (768 KB)

    k_ss_copy<<<B * CHUNKS, TPB, 0, stream>>>(x4, partial4, out4);
    k_mask_zero<<<B * ZBLKS, ZTPB, 0, stream>>>(partial4, out4);
}

// Round 11
// 190.327 us; speedup vs baseline: 1.1006x; 1.0853x over previous
//
#include <hip/hip_runtime.h>

// Problem constants (static shapes from reference)
#define B 64
#define C 2048
#define H 24
#define W 8
#define HW (H * W)            // 192 spatial positions per (b,c)
#define HW4 (HW / 4)          // 48 float4 per channel row
#define CHUNKS 16             // channel chunks per batch
#define CPC (C / CHUNKS)      // 128 channels per chunk
#define RH 8                  // round(0.33 * 24) = 8 rows zeroed
#define CHW4 ((C * HW) / 4)   // float4s per batch = 98304
#define TPB 192               // 3 waves
#define BPB 16                // apply-blocks per batch
#define SLICE (CHW4 / BPB)    // 6144 float4 per block (6144 % 48 == 0)
#define ITERS (SLICE / TPB)   // 32 float4 per thread
#define PF 8                  // prefetched float4 per thread (32 VGPR)

typedef float f32x4 __attribute__((ext_vector_type(4)));

// ---------------------------------------------------------------------------
// REVERT to the Round-5 build (best measured: 189.3 us, absmax 0).
// Session ledger for why the fancier structures lost:
//  - cg::grid.sync (R3):           +200 us  (global barrier over 1024 blocks)
//  - semaphore, acquire-poll (R6): k_one 153 us (per-poll cache invalidates)
//  - semaphore, relaxed+fence (R7): k_one 168 us (agent-fence L2 maintenance)
//  - fused copy, NT stores (R8/R10): k1 63 us (store-ack serialization;
//    register staging defeated by compiler, VGPR=36)
//  - fused copy, regular stores (R9): fills 59->73 us (dirty-line writeback)
// This build: k_ss (read-only sumsq) + k_mask_apply (rank + NT apply).
// ---------------------------------------------------------------------------

// ---------------------------------------------------------------------------
// Kernel A: partial sum of squares over a channel chunk.
// grid = B*CHUNKS, block = 192 (3 waves). 16 B/lane coalesced dwordx4 loads;
// LDS reduce across 4 channel subgroups.
// ---------------------------------------------------------------------------
__global__ __launch_bounds__(TPB) void k_ss(const f32x4* __restrict__ x4,
                                            f32x4* __restrict__ partial4) {
    const int blk = blockIdx.x;
    const int b = blk / CHUNKS;
    const int chunk = blk % CHUNKS;
    const int t = threadIdx.x;
    const int q = t % HW4;   // float4 spatial position
    const int g = t / HW4;   // channel subgroup (0..3)

    const f32x4* p = x4 + (size_t)(b * C + chunk * CPC + g) * HW4 + q;
    f32x4 acc = {0.f, 0.f, 0.f, 0.f};
    #pragma unroll
    for (int j = 0; j < CPC / 4; ++j) {          // 32 iters
        const f32x4 v = p[(size_t)j * 4 * HW4];
        acc += v * v;
    }
    __shared__ f32x4 sm[4][HW4];  // 3 KB
    sm[g][q] = acc;
    __syncthreads();
    if (t < HW4)
        partial4[(size_t)blk * HW4 + t] =
            (sm[0][t] + sm[1][t]) + (sm[2][t] + sm[3][t]);
}

// ---------------------------------------------------------------------------
// Kernel B: fused mask + apply. grid = B*BPB blocks, block = 192.
// Each block REDUNDANTLY ranks its batch's rows from the 12 KB of partials
// (L2-resident; verbatim verified shuffle math incl. tie-break), then applies
// the mask to its 98 KB slice of x (L3-warm re-read). First PF float4 are
// prefetched into registers BEFORE the barrier so their latency hides under
// the rank phase. NT stores keep out from dirtying L2/L3 (fills stay fast).
// No cross-block sync anywhere.
// ---------------------------------------------------------------------------
__global__ __launch_bounds__(TPB) void k_mask_apply(const f32x4* __restrict__ x4,
                                                    const f32x4* __restrict__ partial4,
                                                    f32x4* __restrict__ out4) {
    const int blk = blockIdx.x;
    const int b = blk / BPB;
    const int sub = blk % BPB;
    const int t = threadIdx.x;
    __shared__ float smask[H];

    // ---- Prefetch (independent of mask; overlaps the rank phase) ----
    const size_t base = (size_t)b * CHW4 + (size_t)sub * SLICE + t;
    f32x4 pf[PF];
    #pragma unroll
    for (int k = 0; k < PF; ++k) pf[k] = x4[base + (size_t)k * TPB];

    // ---- Rank rows (wave 0 only; verbatim verified math) ----
    if (t < 64) {
        f32x4 s = {0.f, 0.f, 0.f, 0.f};
        if (t < HW4) {
            #pragma unroll
            for (int ch = 0; ch < CHUNKS; ++ch)  // fixed order: deterministic
                s += partial4[(size_t)(b * CHUNKS + ch) * HW4 + t];
        }
        float m = fmaxf(fmaxf(s.x, s.y), fmaxf(s.z, s.w));
        m = fmaxf(m, __shfl_xor(m, 1));  // row h max now at lane 2h
        const float my = __shfl(m, 2 * (t < H ? t : 0));
        int cnt = 0;
        #pragma unroll
        for (int h = 0; h < H; ++h) {
            const float o = __shfl(m, 2 * h);
            if (o > my || (o == my && h > t)) ++cnt;  // stable-argsort tie-break
        }
        if (t < H) smask[t] = (cnt < RH) ? 0.0f : 1.0f;
    }
    __syncthreads();

    // ---- Apply. Block stride ≡ 0 mod 48 -> h is CONSTANT per thread. ----
    const float m = smask[(t % (2 * H)) >> 1];
    #pragma unroll
    for (int k = 0; k < PF; ++k)
        __builtin_nontemporal_store(pf[k] * m, (f32x4*)(out4 + base + (size_t)k * TPB));
    #pragma unroll
    for (int k = PF; k < ITERS; ++k) {
        const size_t e = base + (size_t)k * TPB;
        __builtin_nontemporal_store(x4[e] * m, (f32x4*)(out4 + e));
    }
}

// ---------------------------------------------------------------------------
extern "C" void kernel_launch(void* const* d_in, const int* in_sizes, int n_in,
                              void* d_out, int out_size, void* d_ws, size_t ws_size,
                              hipStream_t stream) {
    const f32x4* x4 = (const f32x4*)d_in[0];
    f32x4* out4 = (f32x4*)d_out;
    f32x4* partial4 = (f32x4*)d_ws;  // B*CHUNKS*HW floats (768 KB)

    k_ss<<<B * CHUNKS, TPB, 0, stream>>>(x4, partial4);
    k_mask_apply<<<B * BPB, TPB, 0, stream>>>(x4, partial4, out4);
}